// Round 1
// baseline (1627.500 us; speedup 1.0000x reference)
//
#include <hip/hip_runtime.h>
#include <hip/hip_bf16.h>

#define N_NODES_C 100000
#define IN_DIM 128
#define OUT_DIM 64
#define BN_EPS 1e-5f

// ---------------- kernels ----------------

__global__ __launch_bounds__(256) void k_degree(const int* __restrict__ dst, int E,
                                                int* __restrict__ deg) {
    int i = blockIdx.x * 256 + threadIdx.x;
    if (i < E) atomicAdd(&deg[dst[i]], 1);
}

__global__ __launch_bounds__(256) void k_dinv(const int* __restrict__ deg,
                                              float* __restrict__ dinv, int N) {
    int i = blockIdx.x * 256 + threadIdx.x;
    if (i < N) {
        float d = (float)(deg[i] + 1);   // +1 self loop
        dinv[i] = rsqrtf(d);
    }
}

// h = x @ W ; agg initialized with self-loop term h * dinv^2  (= h / deg)
// One wave per node: lane = output dim. W staged in LDS (32 KB), x rows in LDS.
__global__ __launch_bounds__(256) void k_gemm(const float* __restrict__ x,
                                              const float* __restrict__ W,
                                              const float* __restrict__ dinv,
                                              float* __restrict__ h,
                                              float* __restrict__ agg, int N) {
    __shared__ float Wl[IN_DIM * OUT_DIM];  // 32 KB
    __shared__ float xl[4 * IN_DIM];        // 2 KB

    // cooperative load of W: 8192 floats = 2048 float4, 8 per thread
    for (int i = threadIdx.x; i < (IN_DIM * OUT_DIM) / 4; i += 256) {
        ((float4*)Wl)[i] = ((const float4*)W)[i];
    }
    int node0 = blockIdx.x * 4;  // N = 100000 divisible by 4 -> no row tail
    // load 4 x rows: 512 floats = 256 float2, one per thread
    if (node0 < N) {
        ((float2*)xl)[threadIdx.x] =
            ((const float2*)(x + (size_t)node0 * IN_DIM))[threadIdx.x];
    }
    __syncthreads();

    int wave = threadIdx.x >> 6;
    int lane = threadIdx.x & 63;
    int n = node0 + wave;
    if (n < N) {
        float acc = 0.f;
        #pragma unroll
        for (int k = 0; k < IN_DIM; ++k) {
            acc += xl[wave * IN_DIM + k] * Wl[k * OUT_DIM + lane];
        }
        size_t o = (size_t)n * OUT_DIM + lane;
        h[o] = acc;
        float di = dinv[n];
        agg[o] = acc * di * di;   // 1/deg == dinv^2
    }
}

// 16 threads per edge, each handles a float4 chunk of the 64-dim message.
__global__ __launch_bounds__(256) void k_scatter(const int* __restrict__ src,
                                                 const int* __restrict__ dst, int E,
                                                 const float* __restrict__ dinv,
                                                 const float* __restrict__ h,
                                                 float* __restrict__ agg) {
    int t = blockIdx.x * 256 + threadIdx.x;
    int e = t >> 4;
    if (e >= E) return;
    int c = t & 15;
    int s = src[e];
    int d = dst[e];
    float ne = dinv[s] * dinv[d];
    float4 hv = ((const float4*)(h + (size_t)s * OUT_DIM))[c];
    float* ap = agg + (size_t)d * OUT_DIM + (size_t)c * 4;
    atomicAdd(ap + 0, hv.x * ne);
    atomicAdd(ap + 1, hv.y * ne);
    atomicAdd(ap + 2, hv.z * ne);
    atomicAdd(ap + 3, hv.w * ne);
}

// out = relu((agg + b - mean) * gamma * rsqrt(var+eps) + beta), float4-vectorized
__global__ __launch_bounds__(256) void k_epi(const float* __restrict__ agg,
                                             const float* __restrict__ b,
                                             const float* __restrict__ gamma,
                                             const float* __restrict__ beta,
                                             const float* __restrict__ mean,
                                             const float* __restrict__ var,
                                             float* __restrict__ out, int nvec) {
    int t = blockIdx.x * 256 + threadIdx.x;
    if (t >= nvec) return;
    int dbase = (t & 15) * 4;  // (t*4) % 64
    float4 a = ((const float4*)agg)[t];
    float va[4] = {a.x, a.y, a.z, a.w};
    float4 o;
    float* op = (float*)&o;
    #pragma unroll
    for (int j = 0; j < 4; ++j) {
        int d = dbase + j;
        float s = gamma[d] * rsqrtf(var[d] + BN_EPS);
        float v = (va[j] + b[d] - mean[d]) * s + beta[d];
        op[j] = v > 0.f ? v : 0.f;
    }
    ((float4*)out)[t] = o;
}

// ---------------- launcher ----------------

extern "C" void kernel_launch(void* const* d_in, const int* in_sizes, int n_in,
                              void* d_out, int out_size, void* d_ws, size_t ws_size,
                              hipStream_t stream) {
    const float* x     = (const float*)d_in[0];
    const int*   edges = (const int*)d_in[1];
    const float* W     = (const float*)d_in[2];
    const float* b     = (const float*)d_in[3];
    const float* gamma = (const float*)d_in[4];
    const float* beta  = (const float*)d_in[5];
    const float* rmean = (const float*)d_in[6];
    const float* rvar  = (const float*)d_in[7];
    float* out = (float*)d_out;

    int N = in_sizes[0] / IN_DIM;
    int E = in_sizes[1] / 2;
    const int* src = edges;
    const int* dst = edges + E;

    // workspace layout
    char* ws = (char*)d_ws;
    size_t hN = (size_t)N * OUT_DIM * sizeof(float);   // 25.6 MB
    float* h    = (float*)(ws);
    float* agg  = (float*)(ws + hN);
    int*   deg  = (int*)  (ws + 2 * hN);
    float* dinv = (float*)(ws + 2 * hN + (size_t)N * sizeof(int));

    hipMemsetAsync(deg, 0, (size_t)N * sizeof(int), stream);

    k_degree<<<(E + 255) / 256, 256, 0, stream>>>(dst, E, deg);
    k_dinv<<<(N + 255) / 256, 256, 0, stream>>>(deg, dinv, N);
    k_gemm<<<(N + 3) / 4, 256, 0, stream>>>(x, W, dinv, h, agg, N);

    long long tscatter = (long long)E * 16;
    k_scatter<<<(int)((tscatter + 255) / 256), 256, 0, stream>>>(src, dst, E, dinv, h, agg);

    int nvec = N * (OUT_DIM / 4);
    k_epi<<<(nvec + 255) / 256, 256, 0, stream>>>(agg, b, gamma, beta, rmean, rvar, out, nvec);
}

// Round 2
// 416.006 us; speedup vs baseline: 3.9122x; 3.9122x over previous
//
#include <hip/hip_runtime.h>
#include <hip/hip_bf16.h>

#define IN_DIM 128
#define OUT_DIM 64
#define BN_EPS 1e-5f
#define SCAN_BLK 1024   // elements per scan1 block (256 thr x 4)

// ---------------- kernels ----------------

__global__ __launch_bounds__(256) void k_degree(const int* __restrict__ dst, int E,
                                                int* __restrict__ deg) {
    int i = blockIdx.x * 256 + threadIdx.x;
    if (i < E) atomicAdd(&deg[dst[i]], 1);
}

// block-level exclusive scan (1024 elems/block) -> per-elem exclusive, block sums
__global__ __launch_bounds__(256) void k_scan1(const int* __restrict__ deg, int N,
                                               int* __restrict__ offs,
                                               int* __restrict__ bsum) {
    __shared__ int sh[256];
    int base = blockIdx.x * SCAN_BLK + threadIdx.x * 4;
    int v[4]; int s = 0;
    #pragma unroll
    for (int j = 0; j < 4; ++j) {
        int idx = base + j;
        v[j] = (idx < N) ? deg[idx] : 0;
        s += v[j];
    }
    sh[threadIdx.x] = s;
    __syncthreads();
    for (int d = 1; d < 256; d <<= 1) {
        int t = (threadIdx.x >= d) ? sh[threadIdx.x - d] : 0;
        __syncthreads();
        sh[threadIdx.x] += t;
        __syncthreads();
    }
    int run = sh[threadIdx.x] - s;   // exclusive prefix of this thread
    #pragma unroll
    for (int j = 0; j < 4; ++j) {
        int idx = base + j;
        if (idx < N) offs[idx] = run;
        run += v[j];
    }
    if (threadIdx.x == 255) bsum[blockIdx.x] = sh[255];
}

// scan of block sums (nb <= 128), single block of 128 threads
__global__ __launch_bounds__(128) void k_scan2(const int* __restrict__ bsum, int nb,
                                               int* __restrict__ bpre) {
    __shared__ int sh[128];
    int t = threadIdx.x;
    int v = (t < nb) ? bsum[t] : 0;
    sh[t] = v;
    __syncthreads();
    for (int d = 1; d < 128; d <<= 1) {
        int tv = (t >= d) ? sh[t - d] : 0;
        __syncthreads();
        sh[t] += tv;
        __syncthreads();
    }
    if (t < nb) bpre[t] = sh[t] - v;   // exclusive
}

// finalize offsets, init cursor, compute dinv = rsqrt(deg+1)  (fused)
__global__ __launch_bounds__(256) void k_scan3(int* __restrict__ offs,
                                               const int* __restrict__ bpre,
                                               const int* __restrict__ deg,
                                               float* __restrict__ dinv,
                                               int* __restrict__ cursor, int N) {
    int i = blockIdx.x * 256 + threadIdx.x;
    if (i >= N) return;
    int o = offs[i] + bpre[i >> 10];
    offs[i] = o;
    cursor[i] = o;
    dinv[i] = rsqrtf((float)(deg[i] + 1));
}

// bin edges into CSR order: sorted[pos] = {src, norm_e}
__global__ __launch_bounds__(256) void k_bin(const int* __restrict__ src,
                                             const int* __restrict__ dst, int E,
                                             const float* __restrict__ dinv,
                                             int* __restrict__ cursor,
                                             int2* __restrict__ sorted) {
    int e = blockIdx.x * 256 + threadIdx.x;
    if (e >= E) return;
    int s = src[e];
    int d = dst[e];
    float ne = dinv[s] * dinv[d];
    int pos = atomicAdd(&cursor[d], 1);
    int2 rec;
    rec.x = s;
    rec.y = __float_as_int(ne);
    sorted[pos] = rec;
}

// h = x @ W.  Block: 16 nodes, 4 waves; each wave computes 4 nodes (lane = out dim).
__global__ __launch_bounds__(256) void k_gemm(const float* __restrict__ x,
                                              const float* __restrict__ W,
                                              float* __restrict__ h, int N) {
    __shared__ float Wl[IN_DIM * OUT_DIM];  // 32 KB
    __shared__ float xl[16 * IN_DIM];       // 8 KB

    for (int i = threadIdx.x; i < (IN_DIM * OUT_DIM) / 4; i += 256)
        ((float4*)Wl)[i] = ((const float4*)W)[i];

    int node0 = blockIdx.x * 16;
    for (int i = threadIdx.x; i < 16 * IN_DIM / 4; i += 256) {
        int n = node0 + (i >> 5);   // 32 float4 per row
        if (n < N)
            ((float4*)xl)[i] = ((const float4*)x)[(size_t)node0 * (IN_DIM / 4) + i];
    }
    __syncthreads();

    int wave = threadIdx.x >> 6;
    int lane = threadIdx.x & 63;
    int nb = node0 + wave * 4;

    float acc[4] = {0.f, 0.f, 0.f, 0.f};
    for (int k0 = 0; k0 < IN_DIM; k0 += 4) {
        float4 xv0 = ((float4*)xl)[((wave * 4 + 0) * IN_DIM + k0) >> 2];
        float4 xv1 = ((float4*)xl)[((wave * 4 + 1) * IN_DIM + k0) >> 2];
        float4 xv2 = ((float4*)xl)[((wave * 4 + 2) * IN_DIM + k0) >> 2];
        float4 xv3 = ((float4*)xl)[((wave * 4 + 3) * IN_DIM + k0) >> 2];
        #pragma unroll
        for (int kk = 0; kk < 4; ++kk) {
            float w = Wl[(k0 + kk) * OUT_DIM + lane];
            acc[0] += ((float*)&xv0)[kk] * w;
            acc[1] += ((float*)&xv1)[kk] * w;
            acc[2] += ((float*)&xv2)[kk] * w;
            acc[3] += ((float*)&xv3)[kk] * w;
        }
    }
    #pragma unroll
    for (int j = 0; j < 4; ++j) {
        int n = nb + j;
        if (n < N) h[(size_t)n * OUT_DIM + lane] = acc[j];
    }
}

// fused: CSR gather-aggregate + self loop + bias + BN + ReLU.  One wave per node.
__global__ __launch_bounds__(256) void k_agg(const int* __restrict__ offs,
                                             const int2* __restrict__ sorted,
                                             const float* __restrict__ dinv,
                                             const float* __restrict__ h,
                                             const float* __restrict__ b,
                                             const float* __restrict__ gamma,
                                             const float* __restrict__ beta,
                                             const float* __restrict__ mean,
                                             const float* __restrict__ var,
                                             float* __restrict__ out, int N, int E) {
    int wid = (blockIdx.x * 256 + threadIdx.x) >> 6;
    int lane = threadIdx.x & 63;
    if (wid >= N) return;
    int n = wid;
    int s0 = offs[n];
    int s1 = (n == N - 1) ? E : offs[n + 1];
    float dn = dinv[n];
    float acc = h[(size_t)n * OUT_DIM + lane] * dn * dn;  // self loop: 1/deg

    int e = s0;
    if (e < s1) {
        int2 r = sorted[e];
        while (true) {
            int s = r.x;
            float ne = __int_as_float(r.y);
            ++e;
            if (e < s1) r = sorted[e];           // prefetch next record
            acc += h[(size_t)s * OUT_DIM + lane] * ne;
            if (e >= s1) break;
        }
    }

    float sc = gamma[lane] * rsqrtf(var[lane] + BN_EPS);
    float v = (acc + b[lane] - mean[lane]) * sc + beta[lane];
    out[(size_t)n * OUT_DIM + lane] = v > 0.f ? v : 0.f;
}

// ---------------- launcher ----------------

extern "C" void kernel_launch(void* const* d_in, const int* in_sizes, int n_in,
                              void* d_out, int out_size, void* d_ws, size_t ws_size,
                              hipStream_t stream) {
    const float* x     = (const float*)d_in[0];
    const int*   edges = (const int*)d_in[1];
    const float* W     = (const float*)d_in[2];
    const float* b     = (const float*)d_in[3];
    const float* gamma = (const float*)d_in[4];
    const float* beta  = (const float*)d_in[5];
    const float* rmean = (const float*)d_in[6];
    const float* rvar  = (const float*)d_in[7];
    float* out = (float*)d_out;

    int N = in_sizes[0] / IN_DIM;
    int E = in_sizes[1] / 2;
    const int* src = edges;
    const int* dst = edges + E;

    // workspace layout (16B-aligned chunks)
    char* ws = (char*)d_ws;
    size_t hB   = (size_t)N * OUT_DIM * sizeof(float);   // 25.6 MB
    size_t eB   = (size_t)E * sizeof(int2);              // 12.8 MB
    size_t nB   = ((size_t)N * sizeof(int) + 255) & ~(size_t)255;
    float* h      = (float*)(ws);
    int2*  sorted = (int2*) (ws + hB);
    int*   deg    = (int*)  (ws + hB + eB);
    int*   offs   = (int*)  (ws + hB + eB + nB);
    int*   cursor = (int*)  (ws + hB + eB + 2 * nB);
    float* dinv   = (float*)(ws + hB + eB + 3 * nB);
    int*   bsum   = (int*)  (ws + hB + eB + 4 * nB);
    int*   bpre   = (int*)  (ws + hB + eB + 4 * nB + 4096);

    int nscan = (N + SCAN_BLK - 1) / SCAN_BLK;   // 98 blocks for N=100K

    hipMemsetAsync(deg, 0, (size_t)N * sizeof(int), stream);

    k_degree<<<(E + 255) / 256, 256, 0, stream>>>(dst, E, deg);
    k_scan1<<<nscan, 256, 0, stream>>>(deg, N, offs, bsum);
    k_scan2<<<1, 128, 0, stream>>>(bsum, nscan, bpre);
    k_scan3<<<(N + 255) / 256, 256, 0, stream>>>(offs, bpre, deg, dinv, cursor, N);
    k_bin<<<(E + 255) / 256, 256, 0, stream>>>(src, dst, E, dinv, cursor, sorted);
    k_gemm<<<(N + 15) / 16, 256, 0, stream>>>(x, W, h, N);
    k_agg<<<(N + 3) / 4, 256, 0, stream>>>(offs, sorted, dinv, h, b, gamma, beta,
                                           rmean, rvar, out, N, E);
}

// Round 3
// 413.898 us; speedup vs baseline: 3.9321x; 1.0051x over previous
//
#include <hip/hip_runtime.h>
#include <hip/hip_bf16.h>

#define IN_DIM 128
#define OUT_DIM 64
#define BN_EPS 1e-5f
#define SCAN_BLK 1024   // elements per scan1 block (256 thr x 4)

// ---------------- kernels ----------------

__global__ __launch_bounds__(256) void k_degree(const int* __restrict__ dst, int E4,
                                                int* __restrict__ deg) {
    int i = blockIdx.x * 256 + threadIdx.x;
    if (i < E4) {
        int4 v = ((const int4*)dst)[i];
        atomicAdd(&deg[v.x], 1);
        atomicAdd(&deg[v.y], 1);
        atomicAdd(&deg[v.z], 1);
        atomicAdd(&deg[v.w], 1);
    }
}

// block-level exclusive scan (1024 elems/block) -> per-elem exclusive, block sums
__global__ __launch_bounds__(256) void k_scan1(const int* __restrict__ deg, int N,
                                               int* __restrict__ offs,
                                               int* __restrict__ bsum) {
    __shared__ int sh[256];
    int base = blockIdx.x * SCAN_BLK + threadIdx.x * 4;
    int v[4]; int s = 0;
    #pragma unroll
    for (int j = 0; j < 4; ++j) {
        int idx = base + j;
        v[j] = (idx < N) ? deg[idx] : 0;
        s += v[j];
    }
    sh[threadIdx.x] = s;
    __syncthreads();
    for (int d = 1; d < 256; d <<= 1) {
        int t = (threadIdx.x >= d) ? sh[threadIdx.x - d] : 0;
        __syncthreads();
        sh[threadIdx.x] += t;
        __syncthreads();
    }
    int run = sh[threadIdx.x] - s;   // exclusive prefix of this thread
    #pragma unroll
    for (int j = 0; j < 4; ++j) {
        int idx = base + j;
        if (idx < N) offs[idx] = run;
        run += v[j];
    }
    if (threadIdx.x == 255) bsum[blockIdx.x] = sh[255];
}

// scan of block sums (nb <= 128), single block of 128 threads
__global__ __launch_bounds__(128) void k_scan2(const int* __restrict__ bsum, int nb,
                                               int* __restrict__ bpre) {
    __shared__ int sh[128];
    int t = threadIdx.x;
    int v = (t < nb) ? bsum[t] : 0;
    sh[t] = v;
    __syncthreads();
    for (int d = 1; d < 128; d <<= 1) {
        int tv = (t >= d) ? sh[t - d] : 0;
        __syncthreads();
        sh[t] += tv;
        __syncthreads();
    }
    if (t < nb) bpre[t] = sh[t] - v;   // exclusive
}

// finalize offsets, init cursor, compute dinv = rsqrt(deg+1)  (fused)
__global__ __launch_bounds__(256) void k_scan3(int* __restrict__ offs,
                                               const int* __restrict__ bpre,
                                               const int* __restrict__ deg,
                                               float* __restrict__ dinv,
                                               int* __restrict__ cursor, int N) {
    int i = blockIdx.x * 256 + threadIdx.x;
    if (i >= N) return;
    int o = offs[i] + bpre[i >> 10];
    offs[i] = o;
    cursor[i] = o;
    dinv[i] = rsqrtf((float)(deg[i] + 1));
}

// bin edges into CSR order: sorted[pos] = src  (4B records, NT store to avoid
// cross-XCD L2 line ping-pong on the scattered writes)
__global__ __launch_bounds__(256) void k_bin(const int* __restrict__ src,
                                             const int* __restrict__ dst, int E,
                                             int* __restrict__ cursor,
                                             int* __restrict__ sorted) {
    int e = blockIdx.x * 256 + threadIdx.x;
    if (e >= E) return;
    int s = src[e];
    int d = dst[e];
    int pos = atomicAdd(&cursor[d], 1);
    __builtin_nontemporal_store(s, &sorted[pos]);
}

// m = (x @ W) * dinv[n].  Block: 16 nodes, 4 waves; each wave computes 4 nodes.
__global__ __launch_bounds__(256) void k_gemm(const float* __restrict__ x,
                                              const float* __restrict__ W,
                                              const float* __restrict__ dinv,
                                              float* __restrict__ m, int N) {
    __shared__ float Wl[IN_DIM * OUT_DIM];  // 32 KB
    __shared__ float xl[16 * IN_DIM];       // 8 KB

    for (int i = threadIdx.x; i < (IN_DIM * OUT_DIM) / 4; i += 256)
        ((float4*)Wl)[i] = ((const float4*)W)[i];

    int node0 = blockIdx.x * 16;
    for (int i = threadIdx.x; i < 16 * IN_DIM / 4; i += 256) {
        int n = node0 + (i >> 5);   // 32 float4 per row
        if (n < N)
            ((float4*)xl)[i] = ((const float4*)x)[(size_t)node0 * (IN_DIM / 4) + i];
    }
    __syncthreads();

    int wave = threadIdx.x >> 6;
    int lane = threadIdx.x & 63;
    int nb = node0 + wave * 4;

    float acc[4] = {0.f, 0.f, 0.f, 0.f};
    for (int k0 = 0; k0 < IN_DIM; k0 += 4) {
        float4 xv0 = ((float4*)xl)[((wave * 4 + 0) * IN_DIM + k0) >> 2];
        float4 xv1 = ((float4*)xl)[((wave * 4 + 1) * IN_DIM + k0) >> 2];
        float4 xv2 = ((float4*)xl)[((wave * 4 + 2) * IN_DIM + k0) >> 2];
        float4 xv3 = ((float4*)xl)[((wave * 4 + 3) * IN_DIM + k0) >> 2];
        #pragma unroll
        for (int kk = 0; kk < 4; ++kk) {
            float w = Wl[(k0 + kk) * OUT_DIM + lane];
            acc[0] += ((float*)&xv0)[kk] * w;
            acc[1] += ((float*)&xv1)[kk] * w;
            acc[2] += ((float*)&xv2)[kk] * w;
            acc[3] += ((float*)&xv3)[kk] * w;
        }
    }
    #pragma unroll
    for (int j = 0; j < 4; ++j) {
        int n = nb + j;
        if (n < N) m[(size_t)n * OUT_DIM + lane] = acc[j] * dinv[n];
    }
}

// fused CSR gather-aggregate + self loop + BN + ReLU.  One wave per node.
// Lane layout: g = lane>>4 (edge slot 0..3), sub = lane&15 (float4 chunk of row).
// Each instruction gathers 4 full rows (1KB/wave); unroll x2 -> 8 rows in flight.
__global__ __launch_bounds__(256) void k_agg(const int* __restrict__ offs,
                                             const int* __restrict__ sorted,
                                             const float* __restrict__ dinv,
                                             const float* __restrict__ m,
                                             const float* __restrict__ b,
                                             const float* __restrict__ gamma,
                                             const float* __restrict__ beta,
                                             const float* __restrict__ mean,
                                             const float* __restrict__ var,
                                             float* __restrict__ out, int N, int E) {
    int wid = (blockIdx.x * 256 + threadIdx.x) >> 6;
    int lane = threadIdx.x & 63;
    if (wid >= N) return;
    int n = wid;
    int s0 = offs[n];
    int s1 = (n == N - 1) ? E : offs[n + 1];
    int g = lane >> 4;
    int sub = lane & 15;

    float4 acc0 = {0.f, 0.f, 0.f, 0.f};
    float4 acc1 = {0.f, 0.f, 0.f, 0.f};
    int e = s0;
    for (; e + 8 <= s1; e += 8) {
        int sA = sorted[e + g];
        int sB = sorted[e + 4 + g];
        float4 ra = ((const float4*)m)[(size_t)sA * 16 + sub];
        float4 rb = ((const float4*)m)[(size_t)sB * 16 + sub];
        acc0.x += ra.x; acc0.y += ra.y; acc0.z += ra.z; acc0.w += ra.w;
        acc1.x += rb.x; acc1.y += rb.y; acc1.z += rb.z; acc1.w += rb.w;
    }
    for (; e < s1; e += 4) {
        int idx = e + g;
        if (idx < s1) {
            int sA = sorted[idx];
            float4 ra = ((const float4*)m)[(size_t)sA * 16 + sub];
            acc0.x += ra.x; acc0.y += ra.y; acc0.z += ra.z; acc0.w += ra.w;
        }
    }
    acc0.x += acc1.x; acc0.y += acc1.y; acc0.z += acc1.z; acc0.w += acc1.w;

    // reduce the 4 edge slots: lanes l, l^16, l^32, l^48 hold same dims
    #pragma unroll
    for (int mask = 16; mask <= 32; mask <<= 1) {
        acc0.x += __shfl_xor(acc0.x, mask, 64);
        acc0.y += __shfl_xor(acc0.y, mask, 64);
        acc0.z += __shfl_xor(acc0.z, mask, 64);
        acc0.w += __shfl_xor(acc0.w, mask, 64);
    }

    if (lane < 16) {
        float4 self = ((const float4*)m)[(size_t)n * 16 + sub];
        float dn = dinv[n];
        float4 gg = ((const float4*)gamma)[sub];
        float4 vv = ((const float4*)var)[sub];
        float4 bb = ((const float4*)b)[sub];
        float4 mm = ((const float4*)mean)[sub];
        float4 be = ((const float4*)beta)[sub];
        float4 o;
        float* op = (float*)&o;
        float av[4] = {acc0.x + self.x, acc0.y + self.y,
                       acc0.z + self.z, acc0.w + self.w};
        float gv[4] = {gg.x, gg.y, gg.z, gg.w};
        float vvv[4] = {vv.x, vv.y, vv.z, vv.w};
        float bv[4] = {bb.x, bb.y, bb.z, bb.w};
        float mv[4] = {mm.x, mm.y, mm.z, mm.w};
        float ev[4] = {be.x, be.y, be.z, be.w};
        #pragma unroll
        for (int j = 0; j < 4; ++j) {
            float sc = gv[j] * rsqrtf(vvv[j] + BN_EPS);
            float v = (av[j] * dn + bv[j] - mv[j]) * sc + ev[j];
            op[j] = v > 0.f ? v : 0.f;
        }
        ((float4*)out)[(size_t)n * 16 + sub] = o;
    }
}

// ---------------- launcher ----------------

extern "C" void kernel_launch(void* const* d_in, const int* in_sizes, int n_in,
                              void* d_out, int out_size, void* d_ws, size_t ws_size,
                              hipStream_t stream) {
    const float* x     = (const float*)d_in[0];
    const int*   edges = (const int*)d_in[1];
    const float* W     = (const float*)d_in[2];
    const float* b     = (const float*)d_in[3];
    const float* gamma = (const float*)d_in[4];
    const float* beta  = (const float*)d_in[5];
    const float* rmean = (const float*)d_in[6];
    const float* rvar  = (const float*)d_in[7];
    float* out = (float*)d_out;

    int N = in_sizes[0] / IN_DIM;
    int E = in_sizes[1] / 2;
    const int* src = edges;
    const int* dst = edges + E;

    // workspace layout (256B-aligned chunks)
    char* ws = (char*)d_ws;
    size_t mB = (size_t)N * OUT_DIM * sizeof(float);              // 25.6 MB
    size_t eB = ((size_t)E * sizeof(int) + 255) & ~(size_t)255;   // 6.4 MB
    size_t nB = ((size_t)N * sizeof(int) + 255) & ~(size_t)255;
    float* m      = (float*)(ws);
    int*   sorted = (int*)  (ws + mB);
    int*   deg    = (int*)  (ws + mB + eB);
    int*   offs   = (int*)  (ws + mB + eB + nB);
    int*   cursor = (int*)  (ws + mB + eB + 2 * nB);
    float* dinv   = (float*)(ws + mB + eB + 3 * nB);
    int*   bsum   = (int*)  (ws + mB + eB + 4 * nB);
    int*   bpre   = (int*)  (ws + mB + eB + 4 * nB + 4096);

    int nscan = (N + SCAN_BLK - 1) / SCAN_BLK;   // 98 blocks for N=100K

    hipMemsetAsync(deg, 0, (size_t)N * sizeof(int), stream);

    int E4 = E / 4;   // E = 1.6M, divisible by 4
    k_degree<<<(E4 + 255) / 256, 256, 0, stream>>>(dst, E4, deg);
    k_scan1<<<nscan, 256, 0, stream>>>(deg, N, offs, bsum);
    k_scan2<<<1, 128, 0, stream>>>(bsum, nscan, bpre);
    k_scan3<<<(N + 255) / 256, 256, 0, stream>>>(offs, bpre, deg, dinv, cursor, N);
    k_gemm<<<(N + 15) / 16, 256, 0, stream>>>(x, W, dinv, m, N);
    k_bin<<<(E + 255) / 256, 256, 0, stream>>>(src, dst, E, cursor, sorted);
    k_agg<<<(N + 3) / 4, 256, 0, stream>>>(offs, sorted, dinv, m, b, gamma, beta,
                                           rmean, rvar, out, N, E);
}